// Round 1
// baseline (893.198 us; speedup 1.0000x reference)
//
#include <hip/hip_runtime.h>
#include <hip/hip_bf16.h>

// Problem constants (verified against in_sizes at runtime where possible)
#define D_OUT 64
#define BM 256
#define BK 16

// ---------------------------------------------------------------------------
// zero int buffer
__global__ void zero_kernel(int* __restrict__ p, int n) {
    int i = blockIdx.x * blockDim.x + threadIdx.x;
    if (i < n) p[i] = 0;
}

// ---------------------------------------------------------------------------
// Dense projection h = A @ W   (A: [n x K] fp32, W: [K x 64] fp32)
// Block: 256 threads, tile BM=256 rows x 64 cols, 8x8 micro-tile per thread.
__global__ __launch_bounds__(256) void gemm_kernel(
    const float* __restrict__ A, const float* __restrict__ W,
    float* __restrict__ H, int n, int K) {
    __shared__ float As[BM][BK + 1];   // +1 pad: conflict-free column reads
    __shared__ float Ws[BK][D_OUT];

    const int tid = threadIdx.x;
    const int row0 = blockIdx.x * BM;
    const int ty = tid >> 3;   // 0..31 -> row group (8 rows each)
    const int tx = tid & 7;    // 0..7  -> col group (8 cols each)

    float acc[8][8];
#pragma unroll
    for (int i = 0; i < 8; i++)
#pragma unroll
        for (int j = 0; j < 8; j++) acc[i][j] = 0.f;

    for (int k0 = 0; k0 < K; k0 += BK) {
        // Load A tile: 256 rows x 16 k = 1024 float4, 4 per thread
#pragma unroll
        for (int l = 0; l < 4; l++) {
            int t = tid + l * 256;        // 0..1023
            int r = t >> 2;               // 0..255
            int kq = (t & 3) * 4;         // 0,4,8,12
            int gr = row0 + r;
            float4 val;
            if (gr < n)
                val = *reinterpret_cast<const float4*>(&A[(size_t)gr * K + k0 + kq]);
            else
                val = make_float4(0.f, 0.f, 0.f, 0.f);
            As[r][kq + 0] = val.x; As[r][kq + 1] = val.y;
            As[r][kq + 2] = val.z; As[r][kq + 3] = val.w;
        }
        // Load W tile: 16 x 64 = 256 float4, 1 per thread
        {
            int k = tid >> 4;             // 0..15
            int cq = (tid & 15) * 4;      // 0..60
            float4 val = *reinterpret_cast<const float4*>(&W[(size_t)(k0 + k) * D_OUT + cq]);
            Ws[k][cq + 0] = val.x; Ws[k][cq + 1] = val.y;
            Ws[k][cq + 2] = val.z; Ws[k][cq + 3] = val.w;
        }
        __syncthreads();

#pragma unroll
        for (int k = 0; k < BK; k++) {
            float a[8], w[8];
#pragma unroll
            for (int i = 0; i < 8; i++) a[i] = As[ty * 8 + i][k];
#pragma unroll
            for (int j = 0; j < 8; j++) w[j] = Ws[k][tx * 8 + j];
#pragma unroll
            for (int i = 0; i < 8; i++)
#pragma unroll
                for (int j = 0; j < 8; j++) acc[i][j] += a[i] * w[j];
        }
        __syncthreads();
    }

#pragma unroll
    for (int i = 0; i < 8; i++) {
        int gr = row0 + ty * 8 + i;
        if (gr < n) {
            float4 v0 = make_float4(acc[i][0], acc[i][1], acc[i][2], acc[i][3]);
            float4 v1 = make_float4(acc[i][4], acc[i][5], acc[i][6], acc[i][7]);
            *reinterpret_cast<float4*>(&H[(size_t)gr * D_OUT + tx * 8]) = v0;
            *reinterpret_cast<float4*>(&H[(size_t)gr * D_OUT + tx * 8 + 4]) = v1;
        }
    }
}

// ---------------------------------------------------------------------------
// Histogram of edge rows
__global__ void hist_kernel(const int* __restrict__ rows, int* __restrict__ counts, int E) {
    int i = blockIdx.x * blockDim.x + threadIdx.x;
    if (i < E) atomicAdd(&counts[rows[i]], 1);
}

// ---------------------------------------------------------------------------
// Single-block exclusive scan of counts[0..n) -> offsets[0..n], cursor copy.
// 1024 threads, 8 elements/thread, 8192 per chunk.
__global__ __launch_bounds__(1024) void scan_kernel(
    const int* __restrict__ counts, int* __restrict__ offsets,
    int* __restrict__ cursor, int n, int total_edges) {
    __shared__ int wsum[17];
    const int tid = threadIdx.x;
    const int lane = tid & 63;
    const int wid = tid >> 6;  // 0..15
    int carry = 0;

    for (int base = 0; base < n; base += 8192) {
        int idx0 = base + tid * 8;
        int v[8];
#pragma unroll
        for (int j = 0; j < 8; j++) {
            int ix = idx0 + j;
            v[j] = (ix < n) ? counts[ix] : 0;
        }
        // local inclusive scan
#pragma unroll
        for (int j = 1; j < 8; j++) v[j] += v[j - 1];
        int tsum = v[7];

        // wave-level inclusive scan of per-thread sums
        int x = tsum;
#pragma unroll
        for (int d = 1; d < 64; d <<= 1) {
            int y = __shfl_up(x, d, 64);
            if (lane >= d) x += y;
        }
        if (lane == 63) wsum[wid] = x;
        __syncthreads();

        // wave 0 scans the 16 wave sums (sources always active: d <= 8)
        if (tid < 16) {
            int w = wsum[tid];
            int xx = w;
#pragma unroll
            for (int d = 1; d < 16; d <<= 1) {
                int y = __shfl_up(xx, d, 64);
                if (tid >= d) xx += y;
            }
            wsum[tid] = xx - w;          // exclusive wave base
            if (tid == 15) wsum[16] = xx; // chunk total
        }
        __syncthreads();

        int base_excl = carry + wsum[wid] + (x - tsum);
#pragma unroll
        for (int j = 0; j < 8; j++) {
            int ix = idx0 + j;
            if (ix < n) {
                int e = base_excl + ((j == 0) ? 0 : v[j - 1]);
                offsets[ix] = e;
                cursor[ix] = e;
            }
        }
        carry += wsum[16];
        __syncthreads();  // protect wsum before next iteration's writes
    }
    if (tid == 0) offsets[n] = total_edges;
}

// ---------------------------------------------------------------------------
// Bucket edges by row (CSR build)
__global__ void scatter_kernel(
    const int* __restrict__ rows, const int* __restrict__ cols,
    const float* __restrict__ vals, int* __restrict__ cursor,
    int* __restrict__ scol, float* __restrict__ sval, int E) {
    int i = blockIdx.x * blockDim.x + threadIdx.x;
    if (i < E) {
        int r = rows[i];
        int p = atomicAdd(&cursor[r], 1);
        scol[p] = cols[i];
        sval[p] = vals[i];
    }
}

// ---------------------------------------------------------------------------
// Aggregate: one wave per output row, lane = output column. relu at the end.
__global__ void agg_kernel(
    const float* __restrict__ h, const int* __restrict__ offsets,
    const int* __restrict__ scol, const float* __restrict__ sval,
    float* __restrict__ out, int n) {
    int gw = (int)((blockIdx.x * (size_t)blockDim.x + threadIdx.x) >> 6);
    int lane = threadIdx.x & 63;
    if (gw >= n) return;
    int s = offsets[gw];
    int e = offsets[gw + 1];
    float acc = 0.f;
    for (int i = s; i < e; i++) {
        int c = scol[i];
        float v = sval[i];
        acc += v * h[(size_t)c * D_OUT + lane];
    }
    out[(size_t)gw * D_OUT + lane] = fmaxf(acc, 0.f);
}

// ---------------------------------------------------------------------------
extern "C" void kernel_launch(void* const* d_in, const int* in_sizes, int n_in,
                              void* d_out, int out_size, void* d_ws, size_t ws_size,
                              hipStream_t stream) {
    const float* A    = (const float*)d_in[0];   // inputs [N, D_IN]
    const float* W    = (const float*)d_in[1];   // weight [D_IN, 64]
    const float* vals = (const float*)d_in[2];   // adj_vals [E]
    const int*   rows = (const int*)d_in[3];     // adj_rows [E]
    const int*   cols = (const int*)d_in[4];     // adj_cols [E]
    float* out = (float*)d_out;

    const int N = out_size / D_OUT;              // 100000
    const int K = in_sizes[1] / D_OUT;           // 512
    const int E = in_sizes[2];                   // 1600000

    // workspace layout
    char* ws = (char*)d_ws;
    float* h       = (float*)ws;                               // N*64 floats
    int*   counts  = (int*)(ws + (size_t)N * D_OUT * 4);       // N
    int*   offsets = counts + N;                               // N+1
    int*   cursor  = offsets + N + 1;                          // N
    int*   scol    = cursor + N;                               // E
    float* sval    = (float*)(scol + E);                       // E

    zero_kernel<<<(N + 255) / 256, 256, 0, stream>>>(counts, N);
    gemm_kernel<<<(N + BM - 1) / BM, 256, 0, stream>>>(A, W, h, N, K);
    hist_kernel<<<(E + 255) / 256, 256, 0, stream>>>(rows, counts, E);
    scan_kernel<<<1, 1024, 0, stream>>>(counts, offsets, cursor, N, E);
    scatter_kernel<<<(E + 255) / 256, 256, 0, stream>>>(rows, cols, vals, cursor, scol, sval, E);
    agg_kernel<<<((size_t)N * D_OUT + 255) / 256, 256, 0, stream>>>(h, offsets, scol, sval, out, N);
}

// Round 2
// 592.157 us; speedup vs baseline: 1.5084x; 1.5084x over previous
//
#include <hip/hip_runtime.h>
#include <hip/hip_bf16.h>

#define D_OUT 64
#define K_DIM 512

using short8  = __attribute__((ext_vector_type(8))) short;
using floatx4 = __attribute__((ext_vector_type(4))) float;

__device__ inline unsigned short f32_to_bf16(float f) {
    unsigned int u = __float_as_uint(f);
    u += 0x7FFFu + ((u >> 16) & 1u);   // round-to-nearest-even
    return (unsigned short)(u >> 16);
}

// ---------------------------------------------------------------------------
__global__ void zero_kernel(int* __restrict__ p, int n) {
    int i = blockIdx.x * blockDim.x + threadIdx.x;
    if (i < n) p[i] = 0;
}

// ---------------------------------------------------------------------------
// Wt[n][k] = bf16(W[k][n]) : 64 x 512 bf16 (64 KB, L2-resident afterwards)
__global__ void wt_kernel(const float* __restrict__ W, unsigned short* __restrict__ wt) {
    int i = blockIdx.x * blockDim.x + threadIdx.x;
    if (i < D_OUT * K_DIM) {
        int n = i >> 9;        // / 512
        int k = i & 511;
        wt[i] = f32_to_bf16(W[k * D_OUT + n]);
    }
}

// ---------------------------------------------------------------------------
// h = A @ W via bf16 MFMA. Block = 256 thr = 4 waves; wave = 16 rows x 64 cols.
// No LDS. A fragments straight from global fp32 (coalesced 32 B/lane per
// k-step), converted in-register. B fragments from Wt (L2-hot).
__global__ __launch_bounds__(256) void gemm_kernel(
    const float* __restrict__ A, const unsigned short* __restrict__ wt,
    float* __restrict__ H, int n) {
    const int tid  = threadIdx.x;
    const int wv   = tid >> 6;
    const int lane = tid & 63;
    const int ln   = lane & 15;
    const int quad = lane >> 4;           // 0..3
    const int row0 = blockIdx.x * 64 + wv * 16;

    int arow = row0 + ln;
    if (arow >= n) arow = n - 1;          // clamp (stores are guarded)
    const float* Arow = A + (size_t)arow * K_DIM;
    const unsigned short* wb = wt + (size_t)ln * K_DIM;

    floatx4 acc0 = {0.f, 0.f, 0.f, 0.f};
    floatx4 acc1 = {0.f, 0.f, 0.f, 0.f};
    floatx4 acc2 = {0.f, 0.f, 0.f, 0.f};
    floatx4 acc3 = {0.f, 0.f, 0.f, 0.f};

#pragma unroll 4
    for (int ks = 0; ks < K_DIM; ks += 32) {
        const int koff = ks + quad * 8;   // 8 consecutive k per lane
        floatx4 a0 = *reinterpret_cast<const floatx4*>(Arow + koff);
        floatx4 a1 = *reinterpret_cast<const floatx4*>(Arow + koff + 4);
        short8 af;
        af[0] = (short)f32_to_bf16(a0[0]);
        af[1] = (short)f32_to_bf16(a0[1]);
        af[2] = (short)f32_to_bf16(a0[2]);
        af[3] = (short)f32_to_bf16(a0[3]);
        af[4] = (short)f32_to_bf16(a1[0]);
        af[5] = (short)f32_to_bf16(a1[1]);
        af[6] = (short)f32_to_bf16(a1[2]);
        af[7] = (short)f32_to_bf16(a1[3]);
        short8 b0 = *reinterpret_cast<const short8*>(wb + koff);
        short8 b1 = *reinterpret_cast<const short8*>(wb + 16 * K_DIM + koff);
        short8 b2 = *reinterpret_cast<const short8*>(wb + 32 * K_DIM + koff);
        short8 b3 = *reinterpret_cast<const short8*>(wb + 48 * K_DIM + koff);
        acc0 = __builtin_amdgcn_mfma_f32_16x16x32_bf16(af, b0, acc0, 0, 0, 0);
        acc1 = __builtin_amdgcn_mfma_f32_16x16x32_bf16(af, b1, acc1, 0, 0, 0);
        acc2 = __builtin_amdgcn_mfma_f32_16x16x32_bf16(af, b2, acc2, 0, 0, 0);
        acc3 = __builtin_amdgcn_mfma_f32_16x16x32_bf16(af, b3, acc3, 0, 0, 0);
    }

    // C/D layout: col = lane&15, row = quad*4 + reg  [verified m89]
#pragma unroll
    for (int r = 0; r < 4; r++) {
        int gr = row0 + quad * 4 + r;
        if (gr < n) {
            float* Hr = H + (size_t)gr * D_OUT;
            Hr[ln]      = acc0[r];
            Hr[16 + ln] = acc1[r];
            Hr[32 + ln] = acc2[r];
            Hr[48 + ln] = acc3[r];
        }
    }
}

// ---------------------------------------------------------------------------
__global__ void hist_kernel(const int* __restrict__ rows, int* __restrict__ counts, int E) {
    int i = blockIdx.x * blockDim.x + threadIdx.x;
    if (i < E) atomicAdd(&counts[rows[i]], 1);
}

// ---------------------------------------------------------------------------
// 3-phase scan, chunk = 1024 per block.
__global__ __launch_bounds__(256) void scan1_kernel(
    const int* __restrict__ counts, int* __restrict__ bsum, int n) {
    __shared__ int ws[4];
    const int tid = threadIdx.x, lane = tid & 63, wid = tid >> 6;
    int i0 = blockIdx.x * 1024 + tid * 4;
    int s = 0;
#pragma unroll
    for (int j = 0; j < 4; j++) {
        int ix = i0 + j;
        s += (ix < n) ? counts[ix] : 0;
    }
#pragma unroll
    for (int d = 32; d; d >>= 1) s += __shfl_xor(s, d, 64);
    if (lane == 0) ws[wid] = s;
    __syncthreads();
    if (tid == 0) bsum[blockIdx.x] = ws[0] + ws[1] + ws[2] + ws[3];
}

__global__ __launch_bounds__(1024) void scan2_kernel(
    const int* __restrict__ bsum, int* __restrict__ bbase,
    int* __restrict__ offsets, int nb, int N, int E) {
    __shared__ int wsum[16];
    const int tid = threadIdx.x, lane = tid & 63, wid = tid >> 6;
    int v = (tid < nb) ? bsum[tid] : 0;
    int x = v;
#pragma unroll
    for (int d = 1; d < 64; d <<= 1) {
        int y = __shfl_up(x, d, 64);
        if (lane >= d) x += y;
    }
    if (lane == 63) wsum[wid] = x;
    __syncthreads();
    if (tid < 16) {
        int w = wsum[tid];
        int xx = w;
#pragma unroll
        for (int d = 1; d < 16; d <<= 1) {
            int y = __shfl_up(xx, d, 64);
            if (tid >= d) xx += y;
        }
        wsum[tid] = xx - w;              // exclusive wave base
    }
    __syncthreads();
    if (tid < nb) bbase[tid] = wsum[wid] + (x - v);
    if (tid == 0) offsets[N] = E;
}

__global__ __launch_bounds__(256) void scan3_kernel(
    const int* __restrict__ counts, const int* __restrict__ bbase,
    int* __restrict__ offsets, int* __restrict__ cursor, int n) {
    __shared__ int wsum[4];
    const int tid = threadIdx.x, lane = tid & 63, wid = tid >> 6;
    const int i0 = blockIdx.x * 1024 + tid * 4;
    int v[4];
#pragma unroll
    for (int j = 0; j < 4; j++) {
        int ix = i0 + j;
        v[j] = (ix < n) ? counts[ix] : 0;
    }
#pragma unroll
    for (int j = 1; j < 4; j++) v[j] += v[j - 1];
    int t = v[3];
    int x = t;
#pragma unroll
    for (int d = 1; d < 64; d <<= 1) {
        int y = __shfl_up(x, d, 64);
        if (lane >= d) x += y;
    }
    if (lane == 63) wsum[wid] = x;
    __syncthreads();
    if (tid == 0) {
        int a = 0;
#pragma unroll
        for (int w = 0; w < 4; w++) { int tmp = wsum[w]; wsum[w] = a; a += tmp; }
    }
    __syncthreads();
    int excl = bbase[blockIdx.x] + wsum[wid] + (x - t);
#pragma unroll
    for (int j = 0; j < 4; j++) {
        int ix = i0 + j;
        if (ix < n) {
            int e = excl + ((j == 0) ? 0 : v[j - 1]);
            offsets[ix] = e;
            cursor[ix] = e;
        }
    }
}

// ---------------------------------------------------------------------------
__global__ void scatter_kernel(
    const int* __restrict__ rows, const int* __restrict__ cols,
    const float* __restrict__ vals, int* __restrict__ cursor,
    int* __restrict__ scol, float* __restrict__ sval, int E) {
    int i = blockIdx.x * blockDim.x + threadIdx.x;
    if (i < E) {
        int r = rows[i];
        int p = atomicAdd(&cursor[r], 1);
        scol[p] = cols[i];
        sval[p] = vals[i];
    }
}

// ---------------------------------------------------------------------------
// One wave per row, lane = column. h rows gathered coalesced (256 B).
__global__ __launch_bounds__(256) void agg_kernel(
    const float* __restrict__ h, const int* __restrict__ offsets,
    const int* __restrict__ scol, const float* __restrict__ sval,
    float* __restrict__ out, int n) {
    int gw = blockIdx.x * 4 + (threadIdx.x >> 6);
    int lane = threadIdx.x & 63;
    if (gw >= n) return;
    int s = offsets[gw];
    int e = offsets[gw + 1];
    float acc = 0.f;
    int i = s;
    for (; i + 1 < e; i += 2) {
        int c0 = scol[i], c1 = scol[i + 1];
        float v0 = sval[i], v1 = sval[i + 1];
        acc += v0 * h[(size_t)c0 * D_OUT + lane];
        acc += v1 * h[(size_t)c1 * D_OUT + lane];
    }
    if (i < e) acc += sval[i] * h[(size_t)scol[i] * D_OUT + lane];
    out[(size_t)gw * D_OUT + lane] = fmaxf(acc, 0.f);
}

// ---------------------------------------------------------------------------
extern "C" void kernel_launch(void* const* d_in, const int* in_sizes, int n_in,
                              void* d_out, int out_size, void* d_ws, size_t ws_size,
                              hipStream_t stream) {
    const float* A    = (const float*)d_in[0];
    const float* W    = (const float*)d_in[1];
    const float* vals = (const float*)d_in[2];
    const int*   rows = (const int*)d_in[3];
    const int*   cols = (const int*)d_in[4];
    float* out = (float*)d_out;

    const int N = out_size / D_OUT;          // 100000
    const int E = in_sizes[2];               // 1600000
    const int NB = (N + 1023) / 1024;        // 98

    // workspace layout
    char* ws = (char*)d_ws;
    float*          h       = (float*)ws;                          // N*64 f32
    unsigned short* wt      = (unsigned short*)(ws + (size_t)N * D_OUT * 4);  // 64*512 bf16
    int*            counts  = (int*)((char*)wt + (size_t)D_OUT * K_DIM * 2);  // N
    int*            offsets = counts + N;                          // N+1
    int*            cursor  = offsets + N + 1;                     // N
    int*            bsum    = cursor + N;                          // NB
    int*            bbase   = bsum + NB;                           // NB
    int*            scol    = bbase + NB;                          // E
    float*          sval    = (float*)(scol + E);                  // E

    wt_kernel<<<(D_OUT * K_DIM + 255) / 256, 256, 0, stream>>>(W, wt);
    zero_kernel<<<(N + 255) / 256, 256, 0, stream>>>(counts, N);
    gemm_kernel<<<(N + 63) / 64, 256, 0, stream>>>(A, wt, h, N);
    hist_kernel<<<(E + 255) / 256, 256, 0, stream>>>(rows, counts, E);
    scan1_kernel<<<NB, 256, 0, stream>>>(counts, bsum, N);
    scan2_kernel<<<1, 1024, 0, stream>>>(bsum, bbase, offsets, NB, N, E);
    scan3_kernel<<<NB, 256, 0, stream>>>(counts, bbase, offsets, cursor, N);
    scatter_kernel<<<(E + 255) / 256, 256, 0, stream>>>(rows, cols, vals, cursor, scol, sval, E);
    agg_kernel<<<(N + 3) / 4, 256, 0, stream>>>(h, offsets, scol, sval, out, N);
}